// Round 1
// 5601.434 us; speedup vs baseline: 1.9902x; 1.9902x over previous
//
#include <hip/hip_runtime.h>
#include <hip/hip_bf16.h>
#include <stdint.h>

#define T_STEPS 256
#define BATCH   64
#define HID     512
#define HALF    256
#define NCOLS   1536              // [zr1:512 | g1:256 | zr2:512 | g2:256]
#define MROWS   (T_STEPS * BATCH) // 16384
#define SLICE_N 100
#define SAVED_OFF (2 * BATCH * HID) // 65536 floats into d_out

// swizzled weight stream: per layer, 49152 fragments of 16B (8-wave tiling)
#define SB0 0
#define SB1 16384
#define SB2 24576
#define SB3 40960
#define FRAGS_PER_LAYER 49152

// P layout: [g4][t][slot:12][w:8][lane:64][rr:4] f32
#define PSLOT 2048              // 8*64*4 floats
#define PSTEP (12 * PSLOT)      // floats per (g4, t)

#define RING_D 32               // P1 ring depth (timesteps); ring lives in dead X0
#define NHELP 24                // helper WGs = 1536/64 column tiles

typedef short bf16x8 __attribute__((ext_vector_type(8)));
typedef float f32x4  __attribute__((ext_vector_type(4)));

__device__ __forceinline__ f32x4 mfma16(bf16x8 a, bf16x8 b, f32x4 c) {
  return __builtin_amdgcn_mfma_f32_16x16x32_bf16(a, b, c, 0, 0, 0);
}
__device__ __forceinline__ float sigm_f(float x) {
  return __builtin_amdgcn_rcpf(1.f + __expf(-x));
}
__device__ __forceinline__ float tanh_f(float x) {
  x = fminf(fmaxf(x, -30.f), 30.f);
  float e = __expf(-2.f * x);
  return (1.f - e) * __builtin_amdgcn_rcpf(1.f + e);
}

struct AllW {
  const float* W[8]; // l0: zr1,g1,zr2,g2 ; l1: zr1,g1,zr2,g2
  const float* b[8];
};

// ---------------------------------------------------------------- prep
__global__ void prep_weights(AllW aw, __hip_bfloat16* __restrict__ Wsw,
                             __hip_bfloat16* __restrict__ WxT,
                             float* __restrict__ biasAll,
                             uint32_t* __restrict__ flags) {
  int tid = blockIdx.x * blockDim.x + threadIdx.x;
  if (tid < 1024) flags[tid] = 0u;   // zero sync flags every launch (graph-replay safe)
  const int NW = 2 * FRAGS_PER_LAYER;
  const int NX = 2 * NCOLS * 64;
  if (tid < NW) {
    int l = tid / FRAGS_PER_LAYER, r = tid % FRAGS_PER_LAYER;
    int s, fi;
    if (r < SB1)      { s = 0; fi = r; }
    else if (r < SB2) { s = 1; fi = r - SB1; }
    else if (r < SB3) { s = 2; fi = r - SB2; }
    else              { s = 3; fi = r - SB3; }
    int lane = fi & 63, lrow = lane & 15, lgrp = lane >> 4;
    int zr = (s == 0 || s == 2);
    int w, tau, kt;
    if (zr) { w = fi >> 11; tau = (fi >> 9) & 3; kt = (fi >> 6) & 7; }
    else    { w = fi >> 10; tau = (fi >> 9) & 1; kt = (fi >> 6) & 7; }
    int cb = zr ? ((tau >> 1) * 256 + (tau & 1) * 16 + w * 32) : (w * 32 + tau * 16);
    const float* W = aw.W[l * 4 + s];
    int nc = zr ? 512 : 256;
    int kbase = 512 + kt * 32 + lgrp * 8;
    __hip_bfloat16 frag[8];
#pragma unroll
    for (int e = 0; e < 8; ++e)
      frag[e] = __float2bfloat16(W[(size_t)(kbase + e) * nc + cb + lrow]);
    *(uint4*)&Wsw[(size_t)tid * 8] = *(uint4*)frag;
  } else if (tid < NW + NX) {
    int u = tid - NW;
    int l = u / (NCOLS * 64), r = u % (NCOLS * 64);
    int c = r >> 6, k0 = (r & 63) * 8;
    const float* W; int nc, cc;
    if (c < 512)       { W = aw.W[l*4+0]; nc = 512; cc = c;        }
    else if (c < 768)  { W = aw.W[l*4+1]; nc = 256; cc = c - 512;  }
    else if (c < 1280) { W = aw.W[l*4+2]; nc = 512; cc = c - 768;  }
    else               { W = aw.W[l*4+3]; nc = 256; cc = c - 1280; }
    __hip_bfloat16 frag[8];
#pragma unroll
    for (int e = 0; e < 8; ++e)
      frag[e] = __float2bfloat16(W[(size_t)(k0 + e) * nc + cc]);
    *(uint4*)&WxT[((size_t)l * NCOLS + c) * 512 + k0] = *(uint4*)frag;
  } else if (tid < NW + NX + 2 * NCOLS) {
    int c = tid - NW - NX;
    int l = c / NCOLS, cc = c % NCOLS;
    const float* b; int off;
    if (cc < 512)       { b = aw.b[l*4+0]; off = cc;        }
    else if (cc < 768)  { b = aw.b[l*4+1]; off = cc - 512;  }
    else if (cc < 1280) { b = aw.b[l*4+2]; off = cc - 768;  }
    else                { b = aw.b[l*4+3]; off = cc - 1280; }
    biasAll[c] = b[off];
  }
}

// ---------------------------------------------------------------- embed gather
__global__ void embed_gather(const int* __restrict__ seq, const float* __restrict__ emb,
                             __hip_bfloat16* __restrict__ X0) {
  int i = blockIdx.x * blockDim.x + threadIdx.x; // over 16384*128
  int row = i >> 7, c4 = (i & 127) * 4;
  int idx = seq[row];
  float4 v = *(const float4*)&emb[(size_t)idx * HID + c4];
  union { __hip_bfloat16 h[4]; uint2 u; } pk;
  pk.h[0] = __float2bfloat16(v.x);
  pk.h[1] = __float2bfloat16(v.y);
  pk.h[2] = __float2bfloat16(v.z);
  pk.h[3] = __float2bfloat16(v.w);
  *(uint2*)&X0[(size_t)row * HID + c4] = pk.u;
}

// ---------------------------------------------------------------- P0 = X0 @ WxT^T + bias (bulk, layer 0 only)
__global__ __launch_bounds__(256) void gemm_p(const __hip_bfloat16* __restrict__ A,
                                              const __hip_bfloat16* __restrict__ WT,
                                              const float* __restrict__ bias,
                                              float* __restrict__ Psw) {
  const int tid = threadIdx.x;
  const int lane = tid & 63, w = tid >> 6;
  const int lrow = lane & 15, lgrp = lane >> 4;
  const int n0 = blockIdx.x * 64, m0 = blockIdx.y * 64;
  const int wm = w & 1, wn = w >> 1;
  __shared__ __hip_bfloat16 As[64][72];
  f32x4 acc[2][2];
#pragma unroll
  for (int a = 0; a < 2; ++a)
#pragma unroll
    for (int b = 0; b < 2; ++b) acc[a][b] = (f32x4){0.f, 0.f, 0.f, 0.f};

  const int lr = tid >> 2, lc = (tid & 3) * 16;
  for (int k0 = 0; k0 < 512; k0 += 64) {
    *(uint4*)&As[lr][lc]     = *(const uint4*)&A[((size_t)m0 + lr) * 512 + k0 + lc];
    *(uint4*)&As[lr][lc + 8] = *(const uint4*)&A[((size_t)m0 + lr) * 512 + k0 + lc + 8];
    __syncthreads();
#pragma unroll
    for (int kt = 0; kt < 2; ++kt) {
      bf16x8 a0 = *(const bf16x8*)&As[wm * 32 + lrow][kt * 32 + lgrp * 8];
      bf16x8 a1 = *(const bf16x8*)&As[wm * 32 + 16 + lrow][kt * 32 + lgrp * 8];
      bf16x8 b0 = *(const bf16x8*)&WT[((size_t)n0 + wn * 32 + lrow) * 512 + k0 + kt * 32 + lgrp * 8];
      bf16x8 b1 = *(const bf16x8*)&WT[((size_t)n0 + wn * 32 + 16 + lrow) * 512 + k0 + kt * 32 + lgrp * 8];
      acc[0][0] = mfma16(a0, b0, acc[0][0]);
      acc[0][1] = mfma16(a0, b1, acc[0][1]);
      acc[1][0] = mfma16(a1, b0, acc[1][0]);
      acc[1][1] = mfma16(a1, b1, acc[1][1]);
    }
    __syncthreads();
  }
  const int t = m0 >> 6;
#pragma unroll
  for (int mt = 0; mt < 2; ++mt) {
    int g = wm * 2 + mt;
#pragma unroll
    for (int nt = 0; nt < 2; ++nt) {
      int colb = n0 + wn * 32 + nt * 16; // wave-uniform
      int slot, wt;
      if (colb < 512)       { int c = colb;        wt = (c & 255) >> 5; slot = (c >> 8) * 2 + ((c >> 4) & 1); }
      else if (colb < 768)  { int c = colb - 512;  wt = c >> 5;         slot = 4 + ((c >> 4) & 1); }
      else if (colb < 1280) { int c = colb - 768;  wt = (c & 255) >> 5; slot = 6 + (c >> 8) * 2 + ((c >> 4) & 1); }
      else                  { int c = colb - 1280; wt = c >> 5;         slot = 10 + ((c >> 4) & 1); }
      float bv = bias[colb + lrow];
      float4 v;
      v.x = acc[mt][nt][0] + bv;
      v.y = acc[mt][nt][1] + bv;
      v.z = acc[mt][nt][2] + bv;
      v.w = acc[mt][nt][3] + bv;
      size_t off = (((size_t)g * 256 + t) * 12 + slot) * PSLOT + (size_t)wt * 256 + (size_t)lane * 4;
      *(float4*)&Psw[off] = v;
    }
  }
}

// ---------------------------------------------------------------- fused pipeline
// blocks 0-3: layer-0 recurrence   (publishes cnt0[t])
// blocks 4-7: layer-1 recurrence   (waits cnt1[t]==24, publishes l1prog[g])
// blocks 8-31: P1 helpers, one 64-col tile each, Wx slice resident in LDS
//              (wait cnt0[t] + ring back-pressure on l1prog, publish cnt1[t])
struct SharedMem {
  union {
    struct {
      __hip_bfloat16 h1b[4096], h2b[4096], agb[4096];
      float guard[16384];               // 64KB occupancy limiter (runtime-kept)
    } rec;
    struct {
      __hip_bfloat16 Bs[64][520];       // padded: 1040B row stride -> 2-way banks (free)
      float bias[64];
    } hlp;
  };
};

template <int LAYER>
__device__ void rec_body(const __hip_bfloat16* __restrict__ WswL,
                         const float* __restrict__ Pbase,  // L0: full Psw0; L1: ring
                         float* __restrict__ out,
                         __hip_bfloat16* __restrict__ Hseq,
                         uint32_t* __restrict__ cnt0,
                         uint32_t* __restrict__ cnt1,
                         uint32_t* __restrict__ l1prog,
                         SharedMem& sm, int g4) {
  const int tid = threadIdx.x;
  const int lane = tid & 63, w = tid >> 6;      // w in [0,8)
  const int lrow = lane & 15, lgrp = lane >> 4;
  const int b0 = g4 * 16;

  __hip_bfloat16* const h1b = sm.rec.h1b;
  __hip_bfloat16* const h2b = sm.rec.h2b;
  __hip_bfloat16* const agb = sm.rec.agb;
  float* const ldsguard = sm.rec.guard;

  {
    __hip_bfloat16 z0 = __float2bfloat16(0.f);
    for (int i = tid; i < 4096; i += 512) { h1b[i] = z0; h2b[i] = z0; }
    for (int i = tid; i < 16384; i += 512) ldsguard[i] = (float)i;
    if (LAYER == 1)
      for (int i = tid; i < 16 * SLICE_N; i += 512)
        out[SAVED_OFF + (size_t)(b0 + i / SLICE_N) * SLICE_N + (i % SLICE_N)] = 0.f;
  }

  const bf16x8* Wf = (const bf16x8*)WswL;
  const bf16x8* pz1 = Wf + SB0 + w * 2048 + lane;
  const bf16x8* pg1 = Wf + SB1 + w * 1024 + lane;
  const bf16x8* pz2 = Wf + SB2 + w * 2048 + lane;
  const bf16x8* pg2 = Wf + SB3 + w * 1024 + lane;

  const float* Pg = Pbase +
      (LAYER == 0 ? (size_t)g4 * 256 * PSTEP : (size_t)g4 * RING_D * PSTEP) +
      w * 256 + lane * 4;

  float hr1[2][4] = {{0.f,0.f,0.f,0.f},{0.f,0.f,0.f,0.f}};
  float hr2[2][4] = {{0.f,0.f,0.f,0.f},{0.f,0.f,0.f,0.f}};

  bf16x8 fb[40];
#pragma unroll
  for (int i = 0; i < 32; ++i) fb[i] = pz1[i * 64];
  __syncthreads();

  const float Q23 = 8388608.f, IQ23 = 1.f / 8388608.f;
  const float Q10 = 1024.f,    IQ10 = 1.f / 1024.f;

  const int col0 = w * 32 + lrow, col1 = col0 + 16;
  const int fo0 = ((col0 >> 3) * 16 + lgrp * 4) * 8 + (col0 & 7);
  const int fo1 = ((col1 >> 3) * 16 + lgrp * 4) * 8 + (col1 & 7);

  float z1v[2][4], z2v[2][4];

  for (int t = 0; t < T_STEPS; ++t) {
    if (LAYER == 1) {
      // wait until all 24 helper tiles of P1(t) are published
      if (tid == 0) {
        while (__hip_atomic_load(&cnt1[t], __ATOMIC_RELAXED, __HIP_MEMORY_SCOPE_AGENT) < (uint32_t)NHELP)
          __builtin_amdgcn_s_sleep(2);
      }
      __syncthreads();
      // ring wrap: all re-read addresses were last touched >=32 steps ago ->
      // one agent acquire (L1+L2 inv) per wrap makes every ring re-read provably fresh.
      if (t && (t & (RING_D - 1)) == 0)
        __builtin_amdgcn_fence(__ATOMIC_ACQUIRE, "agent");
    }
    const float* Pp = Pg + (size_t)(LAYER == 0 ? t : (t & (RING_D - 1))) * PSTEP;

    // ========== stage 1: zr1 = sigma(P + h2 @ Uzr1); fb[0..15] <- g1
    {
      float4 pS0 = *(const float4*)&Pp[0 * PSLOT];
      float4 pS1 = *(const float4*)&Pp[1 * PSLOT];
      float4 pS2 = *(const float4*)&Pp[2 * PSLOT];
      float4 pS3 = *(const float4*)&Pp[3 * PSLOT];
      f32x4 az0 = (f32x4){0.f,0.f,0.f,0.f}, az1 = az0, az2 = az0, az3 = az0;
      const bf16x8* ab = (const bf16x8*)h2b;
#pragma unroll
      for (int kt = 0; kt < 8; ++kt) {
        bf16x8 A = ab[kt * 64 + lane];
        az0 = mfma16(A, fb[kt],      az0);
        az1 = mfma16(A, fb[8 + kt],  az1);
        az2 = mfma16(A, fb[16 + kt], az2);
        az3 = mfma16(A, fb[24 + kt], az3);
        fb[kt]     = pg1[kt * 64];
        fb[8 + kt] = pg1[(8 + kt) * 64];
      }
#pragma unroll
      for (int rr = 0; rr < 4; ++rr) {
        z1v[0][rr] = 0.875f * sigm_f(az0[rr] + pS0[rr]) + 0.125f;
        z1v[1][rr] = 0.875f * sigm_f(az1[rr] + pS1[rr]) + 0.125f;
        float r10 = sigm_f(az2[rr] + pS2[rr]);
        float r11 = sigm_f(az3[rr] + pS3[rr]);
        agb[fo0 + rr * 8] = __float2bfloat16(r10 * hr2[0][rr]);
        agb[fo1 + rr * 8] = __float2bfloat16(r11 * hr2[1][rr]);
      }
    }
    __syncthreads();

    // ========== stage 2: g1 = tanh(P + agb @ Ug1); h1 update; fb[0..31] <- zr2
    {
      float4 qG0 = *(const float4*)&Pp[4 * PSLOT];
      float4 qG1 = *(const float4*)&Pp[5 * PSLOT];
      f32x4 ag0 = (f32x4){0.f,0.f,0.f,0.f}, ag1 = ag0;
      const bf16x8* ab = (const bf16x8*)agb;
#pragma unroll
      for (int kt = 0; kt < 8; ++kt) {
        bf16x8 A = ab[kt * 64 + lane];
        ag0 = mfma16(A, fb[kt],     ag0);
        ag1 = mfma16(A, fb[8 + kt], ag1);
        fb[16 + kt] = pz2[(16 + kt) * 64];
        fb[24 + kt] = pz2[(24 + kt) * 64];
        fb[kt]      = pz2[kt * 64];
        fb[8 + kt]  = pz2[(8 + kt) * 64];
      }
#pragma unroll
      for (int nt = 0; nt < 2; ++nt)
#pragma unroll
        for (int rr = 0; rr < 4; ++rr) {
          float gv = tanh_f((nt ? ag1[rr] : ag0[rr]) + (nt ? qG1[rr] : qG0[rr]));
          float z = z1v[nt][rr];
          float zq = floorf(z * Q10) * IQ10;
          float h = hr1[nt][rr];
          h = floorf(h * zq * Q23) * IQ23;
          h = h + rintf((1.f - z) * gv * Q23) * IQ23;
          hr1[nt][rr] = h;
          int fo = (nt ? fo1 : fo0) + rr * 8;
          h1b[fo] = __float2bfloat16(h);
          int col = nt ? col1 : col0;
          int row = lgrp * 4 + rr;
          if (LAYER == 0)
            Hseq[((size_t)t * BATCH + b0 + row) * HID + col] = __float2bfloat16(h);
          if (LAYER == 1 && col < SLICE_N)
            out[SAVED_OFF + (size_t)(t + 1) * (BATCH * SLICE_N) + (b0 + row) * SLICE_N + col] = h;
          if (t == T_STEPS - 1)
            out[(size_t)LAYER * (BATCH * HID) + (b0 + row) * HID + col] = h;
        }
    }
    __syncthreads();

    // ========== stage 3: zr2 = sigma(P + h1 @ Uzr2); fb[0..15] <- g2
    {
      float4 qZ0 = *(const float4*)&Pp[6 * PSLOT];
      float4 qZ1 = *(const float4*)&Pp[7 * PSLOT];
      float4 qZ2 = *(const float4*)&Pp[8 * PSLOT];
      float4 qZ3 = *(const float4*)&Pp[9 * PSLOT];
      f32x4 az0 = (f32x4){0.f,0.f,0.f,0.f}, az1 = az0, az2 = az0, az3 = az0;
      const bf16x8* ab = (const bf16x8*)h1b;
#pragma unroll
      for (int kt = 0; kt < 8; ++kt) {
        bf16x8 A = ab[kt * 64 + lane];
        az0 = mfma16(A, fb[kt],      az0);
        az1 = mfma16(A, fb[8 + kt],  az1);
        az2 = mfma16(A, fb[16 + kt], az2);
        az3 = mfma16(A, fb[24 + kt], az3);
        fb[kt]     = pg2[kt * 64];
        fb[8 + kt] = pg2[(8 + kt) * 64];
      }
#pragma unroll
      for (int rr = 0; rr < 4; ++rr) {
        z2v[0][rr] = 0.875f * sigm_f(az0[rr] + qZ0[rr]) + 0.125f;
        z2v[1][rr] = 0.875f * sigm_f(az1[rr] + qZ1[rr]) + 0.125f;
        float r20 = sigm_f(az2[rr] + qZ2[rr]);
        float r21 = sigm_f(az3[rr] + qZ3[rr]);
        agb[fo0 + rr * 8] = __float2bfloat16(r20 * hr1[0][rr]);
        agb[fo1 + rr * 8] = __float2bfloat16(r21 * hr1[1][rr]);
      }
    }
    __syncthreads();

    // ========== stage 4: g2 = tanh(P + agb @ Ug2); h2 update; fb[0..31] <- zr1(t+1)
    {
      float4 qH0 = *(const float4*)&Pp[10 * PSLOT];
      float4 qH1 = *(const float4*)&Pp[11 * PSLOT];
      f32x4 ag0 = (f32x4){0.f,0.f,0.f,0.f}, ag1 = ag0;
      const bf16x8* ab = (const bf16x8*)agb;
#pragma unroll
      for (int kt = 0; kt < 8; ++kt) {
        bf16x8 A = ab[kt * 64 + lane];
        ag0 = mfma16(A, fb[kt],     ag0);
        ag1 = mfma16(A, fb[8 + kt], ag1);
        fb[16 + kt] = pz1[(16 + kt) * 64];
        fb[24 + kt] = pz1[(24 + kt) * 64];
        fb[kt]      = pz1[kt * 64];
        fb[8 + kt]  = pz1[(8 + kt) * 64];
      }
#pragma unroll
      for (int nt = 0; nt < 2; ++nt)
#pragma unroll
        for (int rr = 0; rr < 4; ++rr) {
          float gv = tanh_f((nt ? ag1[rr] : ag0[rr]) + (nt ? qH1[rr] : qH0[rr]));
          float z = z2v[nt][rr];
          float zq = floorf(z * Q10) * IQ10;
          float h = hr2[nt][rr];
          h = floorf(h * zq * Q23) * IQ23;
          h = h + rintf((1.f - z) * gv * Q23) * IQ23;
          hr2[nt][rr] = h;
          int fo = (nt ? fo1 : fo0) + rr * 8;
          h2b[fo] = __float2bfloat16(h);
          int col = nt ? col1 : col0;
          int row = lgrp * 4 + rr;
          if (LAYER == 0)
            Hseq[((size_t)t * BATCH + b0 + row) * HID + HALF + col] = __float2bfloat16(h);
          if (t == T_STEPS - 1)
            out[(size_t)LAYER * (BATCH * HID) + (b0 + row) * HID + HALF + col] = h;
        }
    }
    __syncthreads();

    if (LAYER == 0) {
      // publish h0(t): flush dirty L2 to L3, then bump counter (L3-coherent atomic)
      if (tid == 0) {
        __builtin_amdgcn_fence(__ATOMIC_RELEASE, "agent");
        __hip_atomic_fetch_add(&cnt0[t], 1u, __ATOMIC_RELAXED, __HIP_MEMORY_SCOPE_AGENT);
      }
    } else {
      // publish progress for ring back-pressure (reads of slot t are drained by the barrier)
      if (tid == 0)
        __hip_atomic_store(&l1prog[g4], (uint32_t)(t + 1), __ATOMIC_RELAXED, __HIP_MEMORY_SCOPE_AGENT);
    }
  }
  if ((uintptr_t)Pbase == 12345u) out[0] = ldsguard[lane];
}

// helper: per-step GEMM tile P1(t)[:, n0:n0+64] = h0(t) @ Wx1-slice + bias
// Identical MFMA shapes / K-order / operands as gemm_p -> bitwise-identical P1.
__device__ void helper_body(const __hip_bfloat16* __restrict__ WxT1,
                            const float* __restrict__ bias1,
                            const __hip_bfloat16* __restrict__ Hseq,
                            float* __restrict__ P1ring,
                            uint32_t* __restrict__ cnt0,
                            uint32_t* __restrict__ cnt1,
                            uint32_t* __restrict__ l1prog,
                            SharedMem& sm, int n) {
  const int tid = threadIdx.x;
  const int lane = tid & 63, w = tid >> 6;
  const int lrow = lane & 15, lgrp = lane >> 4;
  const int n0 = n * 64;

  // resident Wx slice: 64 cols x 512 K bf16 in LDS, loaded once
  for (int i = tid; i < 64 * 64; i += 512) {
    int c = i >> 6, k8 = (i & 63) * 8;
    *(bf16x8*)&sm.hlp.Bs[c][k8] = *(const bf16x8*)&WxT1[(size_t)(n0 + c) * 512 + k8];
  }
  if (tid < 64) sm.hlp.bias[tid] = bias1[n0 + tid];
  __syncthreads();

  const int mt = w & 3, ch = w >> 2;     // row-tile (== g4), col-half
  const int r0 = mt * 16, c0l = ch * 32;

  for (int t = 0; t < T_STEPS; ++t) {
    if (tid == 0) {
      while (__hip_atomic_load(&cnt0[t], __ATOMIC_RELAXED, __HIP_MEMORY_SCOPE_AGENT) < 4u)
        __builtin_amdgcn_s_sleep(2);
      if (t >= RING_D) {
        // WAR: don't overwrite ring slot until layer-1 finished step t-RING_D
        for (;;) {
          uint32_t m0 = __hip_atomic_load(&l1prog[0], __ATOMIC_RELAXED, __HIP_MEMORY_SCOPE_AGENT);
          uint32_t m1 = __hip_atomic_load(&l1prog[1], __ATOMIC_RELAXED, __HIP_MEMORY_SCOPE_AGENT);
          uint32_t m2 = __hip_atomic_load(&l1prog[2], __ATOMIC_RELAXED, __HIP_MEMORY_SCOPE_AGENT);
          uint32_t m3 = __hip_atomic_load(&l1prog[3], __ATOMIC_RELAXED, __HIP_MEMORY_SCOPE_AGENT);
          uint32_t mm = m0 < m1 ? m0 : m1;
          uint32_t nn = m2 < m3 ? m2 : m3;
          mm = mm < nn ? mm : nn;
          if (mm + (uint32_t)(RING_D - 1) >= (uint32_t)t) break;
          __builtin_amdgcn_s_sleep(2);
        }
      }
    }
    __syncthreads();

    const __hip_bfloat16* Arow = &Hseq[((size_t)t * 64 + r0 + lrow) * 512 + lgrp * 8];
    f32x4 a0 = (f32x4){0.f,0.f,0.f,0.f}, a1 = a0;
#pragma unroll
    for (int kt = 0; kt < 16; ++kt) {
      bf16x8 A   = *(const bf16x8*)&Arow[kt * 32];
      bf16x8 bb0 = *(const bf16x8*)&sm.hlp.Bs[c0l + lrow][kt * 32 + lgrp * 8];
      bf16x8 bb1 = *(const bf16x8*)&sm.hlp.Bs[c0l + 16 + lrow][kt * 32 + lgrp * 8];
      a0 = mfma16(A, bb0, a0);
      a1 = mfma16(A, bb1, a1);
    }
#pragma unroll
    for (int nt = 0; nt < 2; ++nt) {
      int colb = n0 + c0l + nt * 16;     // wave-uniform
      int slot, wt;
      if (colb < 512)       { int c = colb;        wt = (c & 255) >> 5; slot = (c >> 8) * 2 + ((c >> 4) & 1); }
      else if (colb < 768)  { int c = colb - 512;  wt = c >> 5;         slot = 4 + ((c >> 4) & 1); }
      else if (colb < 1280) { int c = colb - 768;  wt = (c & 255) >> 5; slot = 6 + (c >> 8) * 2 + ((c >> 4) & 1); }
      else                  { int c = colb - 1280; wt = c >> 5;         slot = 10 + ((c >> 4) & 1); }
      float bv = sm.hlp.bias[c0l + nt * 16 + lrow];
      f32x4 acc = nt ? a1 : a0;
      float4 v;
      v.x = acc[0] + bv; v.y = acc[1] + bv; v.z = acc[2] + bv; v.w = acc[3] + bv;
      size_t off = (((size_t)mt * RING_D + (t & (RING_D - 1))) * 12 + slot) * PSLOT +
                   (size_t)wt * 256 + (size_t)lane * 4;
      *(float4*)&P1ring[off] = v;
    }
    __syncthreads();   // drain all threads' stores into L2
    if (tid == 0) {
      __builtin_amdgcn_fence(__ATOMIC_RELEASE, "agent");   // flush P1 tile to L3
      __hip_atomic_fetch_add(&cnt1[t], 1u, __ATOMIC_RELAXED, __HIP_MEMORY_SCOPE_AGENT);
    }
  }
}

__global__ __attribute__((amdgpu_waves_per_eu(2))) __launch_bounds__(512)
void fused_kernel(const __hip_bfloat16* __restrict__ Wsw,
                  const float* __restrict__ Psw0,
                  float* __restrict__ P1ring,
                  const __hip_bfloat16* __restrict__ WxT1,
                  const float* __restrict__ bias1,
                  float* __restrict__ out,
                  __hip_bfloat16* __restrict__ Hseq,
                  uint32_t* __restrict__ cnt0,
                  uint32_t* __restrict__ cnt1,
                  uint32_t* __restrict__ l1prog) {
  __shared__ SharedMem sm;
  const int bid = blockIdx.x;
  if (bid < 4)
    rec_body<0>(Wsw, Psw0, out, Hseq, cnt0, cnt1, l1prog, sm, bid);
  else if (bid < 8)
    rec_body<1>(Wsw + (size_t)FRAGS_PER_LAYER * 8, P1ring, out, Hseq, cnt0, cnt1, l1prog, sm, bid - 4);
  else
    helper_body(WxT1, bias1, Hseq, P1ring, cnt0, cnt1, l1prog, sm, bid - 8);
}

// ---------------------------------------------------------------- launch
extern "C" void kernel_launch(void* const* d_in, const int* in_sizes, int n_in,
                              void* d_out, int out_size, void* d_ws, size_t ws_size,
                              hipStream_t stream) {
  const int*   seq = (const int*)d_in[0];
  const float* emb = (const float*)d_in[1];
  AllW aw;
  for (int l = 0; l < 2; ++l)
    for (int s = 0; s < 4; ++s) {
      aw.W[l * 4 + s] = (const float*)d_in[2 + l * 8 + s * 2];
      aw.b[l * 4 + s] = (const float*)d_in[2 + l * 8 + s * 2 + 1];
    }

  uint8_t* wp = (uint8_t*)d_ws;
  float* Psw = (float*)wp;                   wp += (size_t)4 * 256 * PSTEP * 4;        // 100.7 MB (P0)
  __hip_bfloat16* X0 = (__hip_bfloat16*)wp;  wp += (size_t)MROWS * HID * 2;            // 16.8 MB (X0, then P1 ring)
  __hip_bfloat16* H0 = (__hip_bfloat16*)wp;  wp += (size_t)MROWS * HID * 2;            // 16.8 MB
  __hip_bfloat16* Wsw = (__hip_bfloat16*)wp; wp += (size_t)2 * FRAGS_PER_LAYER * 8 * 2;// 1.6 MB
  __hip_bfloat16* WxT = (__hip_bfloat16*)wp; wp += (size_t)2 * NCOLS * 512 * 2;        // 3.1 MB
  float* biasAll = (float*)wp;               wp += (size_t)2 * NCOLS * 4;
  uint32_t* flags = (uint32_t*)wp;           wp += 4096;                               // cnt0|cnt1|l1prog
  uint32_t* cnt0 = flags;
  uint32_t* cnt1 = flags + 256;
  uint32_t* l1prog = flags + 512;

  float* out = (float*)d_out;

  const int prepN = (2 * FRAGS_PER_LAYER + 2 * NCOLS * 64 + 2 * NCOLS + 255) / 256;
  prep_weights<<<prepN, 256, 0, stream>>>(aw, Wsw, WxT, biasAll, flags);
  embed_gather<<<(MROWS * 128) / 256, 256, 0, stream>>>(seq, emb, X0);

  gemm_p<<<dim3(24, 256), 256, 0, stream>>>(X0, WxT, biasAll, Psw);
  // X0 is dead after gemm_p -> reuse its first 12.6 MB as the P1 ring (32 steps deep)
  fused_kernel<<<4 + 4 + NHELP, 512, 0, stream>>>(
      Wsw, Psw, (float*)X0, WxT + (size_t)NCOLS * 512, biasAll + NCOLS,
      out, H0, cnt0, cnt1, l1prog);
}